// Round 23
// baseline (87.893 us; speedup 1.0000x reference)
//
#include <hip/hip_runtime.h>
#include <cstddef>
#include <cstdint>

#define NB 256
#define CH 256
#define NTOK 320
#define NPW 320
#define NCOL 323
#define LN_EPS 1e-5f

typedef short short8 __attribute__((ext_vector_type(8)));
typedef float floatx4 __attribute__((ext_vector_type(4)));

__device__ __forceinline__ uint16_t f2bf(float f) {
  uint32_t u = __builtin_bit_cast(uint32_t, f);
  u += 0x7FFFu + ((u >> 16) & 1u);          // round-to-nearest-even
  return (uint16_t)(u >> 16);
}

__device__ __forceinline__ void gload_lds16(const void* g, void* l) {
  __builtin_amdgcn_global_load_lds(
      (const __attribute__((address_space(1))) unsigned int*)g,
      (__attribute__((address_space(3))) unsigned int*)l, 16, 0, 0);
}

// ------ K00: w3tk[k/8][n][k%8] = bf16(w[k][3+n]); w012[tap][k] --------------
__global__ __launch_bounds__(256) void wprep_kernel(
    const float* __restrict__ w, uint16_t* __restrict__ w3tk,
    float* __restrict__ w012) {
  const int n = blockIdx.x;     // 0..322
  const int k = threadIdx.x;    // 0..255
  if (n < NPW) w3tk[(((k >> 3) * NPW) + n) * 8 + (k & 7)] = f2bf(w[k * NCOL + 3 + n]);
  else         w012[(n - NPW) * 256 + k] = w[k * NCOL + (n - NPW)];
}

// ------ K1: FUSED prep (roles 0-9) | gemm1 (roles 10-13) --------------------
// r22 verbatim (best known: 61.8 us, 48 VGPR, bank conflicts = 0).
__global__ __launch_bounds__(512) void fused1_kernel(
    const float* __restrict__ query, const float* __restrict__ value,
    const float* __restrict__ w012, const float* __restrict__ bl,
    const uint16_t* __restrict__ w3tk,
    uint16_t* __restrict__ rTk, uint16_t* __restrict__ pwk)
{
  __shared__ __align__(16) char smem[36864];
  const int bid = blockIdx.x;
  const int wg  = ((bid & 7) * (NB * 14 / 8)) + (bid >> 3);  // XCD chunking
  const int b   = wg / 14;
  const int role = wg % 14;
  const int t   = threadIdx.x;      // 0..511
  const int wid = t >> 6, lane = t & 63;

  if (role < 10) {
    // =================== prep role ===================
    uint16_t (*rbuf)[256] = (uint16_t(*)[256])smem;   // 16 KB conv output
    const int tile = role;
    const int n0   = tile * 32;
    const bool isval = (tile < 8);
    const float* src = isval ? (value + ((size_t)b * 256 + n0) * CH)
                             : (query + ((size_t)b * 64 + (n0 - 256)) * CH);
    float4 xv[4];
    #pragma unroll
    for (int q = 0; q < 4; ++q)
      xv[q] = *(const float4*)(src + q * 2048 + t * 4);
    const float4 w0 = *(const float4*)(w012 + lane * 4);
    const float4 w1 = *(const float4*)(w012 + 256 + lane * 4);
    const float4 w2 = *(const float4*)(w012 + 512 + lane * 4);
    const float bl0 = bl[0], bl1 = bl[1], bl2 = bl[2];

    #pragma unroll
    for (int q = 0; q < 4; ++q) {
      float p0 = xv[q].x * w0.x, p1 = xv[q].x * w1.x, p2 = xv[q].x * w2.x;
      p0 = fmaf(xv[q].y, w0.y, p0); p1 = fmaf(xv[q].y, w1.y, p1); p2 = fmaf(xv[q].y, w2.y, p2);
      p0 = fmaf(xv[q].z, w0.z, p0); p1 = fmaf(xv[q].z, w1.z, p1); p2 = fmaf(xv[q].z, w2.z, p2);
      p0 = fmaf(xv[q].w, w0.w, p0); p1 = fmaf(xv[q].w, w1.w, p1); p2 = fmaf(xv[q].w, w2.w, p2);
      #pragma unroll
      for (int off = 32; off; off >>= 1) {
        p0 += __shfl_xor(p0, off);
        p1 += __shfl_xor(p1, off);
        p2 += __shfl_xor(p2, off);
      }
      const float d0 = p0 + bl0, d1 = p1 + bl1, d2 = p2 + bl2;
      float xm = __shfl_up(xv[q].w, 1);   if (lane == 0)  xm = 0.0f;
      float xp = __shfl_down(xv[q].x, 1); if (lane == 63) xp = 0.0f;
      const float o0 = fmaf(d0, xm,       fmaf(d1, xv[q].x, d2 * xv[q].y));
      const float o1 = fmaf(d0, xv[q].x,  fmaf(d1, xv[q].y, d2 * xv[q].z));
      const float o2 = fmaf(d0, xv[q].y,  fmaf(d1, xv[q].z, d2 * xv[q].w));
      const float o3 = fmaf(d0, xv[q].z,  fmaf(d1, xv[q].w, d2 * xp));
      ushort4 h;
      h.x = f2bf(fmaxf(o0, 0.0f)); h.y = f2bf(fmaxf(o1, 0.0f));
      h.z = f2bf(fmaxf(o2, 0.0f)); h.w = f2bf(fmaxf(o3, 0.0f));
      *(ushort4*)&rbuf[q * 8 + wid][lane * 4] = h;
    }
    __syncthreads();

    const int c = t & 255, half = t >> 8;
    uint16_t hbuf[16];
    #pragma unroll
    for (int j = 0; j < 16; ++j) hbuf[j] = rbuf[half * 16 + j][c];
    const int g0 = tile * 4 + half * 2;
    *(uint4*)(rTk + (((size_t)b * 40 + g0)     * 256 + c) * 8) = ((const uint4*)hbuf)[0];
    *(uint4*)(rTk + (((size_t)b * 40 + g0 + 1) * 256 + c) * 8) = ((const uint4*)hbuf)[1];

  } else {
    // =================== gemm1 role (8 waves, 4M x 2N) ==============
    uint16_t* as_ = (uint16_t*)smem;              // [2][4096] = 2 x 8 KB
    uint16_t* bs_ = (uint16_t*)(smem + 16384);    // [2][5120] = 2 x 10 KB
    const int sub = role - 10;                    // 0..3
    const int m0  = (sub >> 1) * 128;
    const int n0  = (sub & 1) * 160;
    const int wm = wid >> 1, wn = wid & 1;
    const int lr = lane & 15, lg = lane >> 4;

    const float* gA = value + ((size_t)b * 256 + m0) * 256;

    floatx4 acc[2][5];
    #pragma unroll
    for (int i = 0; i < 2; ++i)
      #pragma unroll
      for (int j = 0; j < 5; ++j)
        acc[i][j] = (floatx4)0.0f;

#define STAGE_B(buf, ks)                                                       \
  {                                                                            \
    {                                                                          \
      const int s = t;                                                         \
      const int g = s / 160, r = s - g * 160;                                  \
      gload_lds16(w3tk + ((((ks) >> 3) + g) * (size_t)NPW + n0 + r) * 8,       \
                  bs_ + (size_t)(buf)*5120 + s * 8);                           \
    }                                                                          \
    if (t < 128) {                                                             \
      const int s = 512 + t;                                                   \
      const int g = s / 160, r = s - g * 160;                                  \
      gload_lds16(w3tk + ((((ks) >> 3) + g) * (size_t)NPW + n0 + r) * 8,       \
                  bs_ + (size_t)(buf)*5120 + s * 8);                           \
    }                                                                          \
  }

#define LOAD_A(ks)                                                             \
  {                                                                            \
    const int row = t >> 2, g = t & 3;                                         \
    const float* p = gA + (size_t)row * 256 + (ks) + g * 8;                    \
    areg0 = *(const float4*)p;                                                 \
    areg1 = *(const float4*)(p + 4);                                           \
  }

#define WRITE_A(buf)                                                           \
  {                                                                            \
    const int row = t >> 2, g = t & 3;                                         \
    short8 h;                                                                  \
    h[0] = (short)f2bf(areg0.x); h[1] = (short)f2bf(areg0.y);                  \
    h[2] = (short)f2bf(areg0.z); h[3] = (short)f2bf(areg0.w);                  \
    h[4] = (short)f2bf(areg1.x); h[5] = (short)f2bf(areg1.y);                  \
    h[6] = (short)f2bf(areg1.z); h[7] = (short)f2bf(areg1.w);                  \
    *(short8*)((char*)(as_ + (size_t)(buf)*4096) +                             \
               (g * 128 + (row ^ (g << 1))) * 16) = h;                         \
  }

    float4 areg0, areg1;
    LOAD_A(0);
    STAGE_B(0, 0);
    WRITE_A(0);
    __syncthreads();

    for (int kt = 0; kt < 8; ++kt) {
      const int cur = kt & 1;
      if (kt < 7) {
        STAGE_B(cur ^ 1, (kt + 1) * 32);
        LOAD_A((kt + 1) * 32);
      }

      short8 af[2], bf[5];
      #pragma unroll
      for (int am = 0; am < 2; ++am) {
        const int row = wm * 32 + am * 16 + lr;
        af[am] = *(const short8*)(as_ + (size_t)cur * 4096 +
                                  (lg * 128 + (row ^ (lg << 1))) * 8);
      }
      #pragma unroll
      for (int bn = 0; bn < 5; ++bn) {
        const int row = wn * 80 + bn * 16 + lr;
        bf[bn] = *(const short8*)(bs_ + (size_t)cur * 5120 + (lg * 160 + row) * 8);
      }
      __builtin_amdgcn_s_setprio(1);          // T5: favor MFMA waves vs prep
      #pragma unroll
      for (int am = 0; am < 2; ++am)
        #pragma unroll
        for (int bn = 0; bn < 5; ++bn)
          acc[am][bn] = __builtin_amdgcn_mfma_f32_16x16x32_bf16(
              af[am], bf[bn], acc[am][bn], 0, 0, 0);
      __builtin_amdgcn_s_setprio(0);

      if (kt < 7) {
        WRITE_A(cur ^ 1);
        __syncthreads();     // protects bs_/as_[cur] reads vs next stage
      }
      // kt==7: no further staging -> final barrier is dead, skip it
    }
#undef STAGE_B
#undef LOAD_A
#undef WRITE_A

    #pragma unroll
    for (int bn = 0; bn < 5; ++bn) {
      const int col = n0 + wn * 80 + bn * 16 + lr;
      const float bias = bl[3 + col];
      #pragma unroll
      for (int am = 0; am < 2; ++am) {
        #pragma unroll
        for (int rg = 0; rg < 4; ++rg) {
          const int row = m0 + wm * 32 + am * 16 + lg * 4 + rg;
          pwk[(((size_t)b * 40 + (col >> 3)) * 256 + row) * 8 + (col & 7)] =
              f2bf(acc[am][bn][rg] + bias);
        }
      }
    }
  }
}

// ------ K2: out = LN(pwk @ rTk^T) * gamma + beta  (MFMA bf16) ---------------
// 256 threads / 4 waves (1M x 4N), BM=64, BN=256, K=320, BK=32.
// Grid NB*4 = 1024 = 4 blocks/CU (was 2): doubled barrier-group interleave.
// A-frags direct from pwk; B double-buffered in LDS.
__global__ __launch_bounds__(256) void gemm2_kernel(
    const uint16_t* __restrict__ pwk, const uint16_t* __restrict__ rTk,
    const float* __restrict__ gamma, const float* __restrict__ beta,
    float* __restrict__ out)
{
  __shared__ uint16_t bs_[2][8192];    // 2 x 16 KB (B: 256x32)
  __shared__ float reds[64][4], redq[64][4];     // 2 KB
  __shared__ float muv[64], rsv[64];             // 512 B
  const int t   = threadIdx.x;          // 0..255
  const int tid = ((blockIdx.x & 7) << 7) + (blockIdx.x >> 3);  // XCD swizzle
  const int b   = tid >> 2;
  const int m0  = (tid & 3) * 64;
  const int wn  = t >> 6, lane = t & 63;    // wave = column quarter
  const int lr = lane & 15, lg = lane >> 4;

  const uint16_t* gA = pwk + (size_t)b * 40 * 256 * 8;

  floatx4 acc[4][4];
  #pragma unroll
  for (int i = 0; i < 4; ++i)
    #pragma unroll
    for (int j = 0; j < 4; ++j)
      acc[i][j] = (floatx4)0.0f;

#define STAGE_B2(buf, ks)                                                      \
  {                                                                            \
    _Pragma("unroll")                                                          \
    for (int q = 0; q < 4; ++q) {                                              \
      const int s = q * 256 + t;                                               \
      const int g = s >> 8, r = s & 255;                                       \
      gload_lds16(rTk + (((size_t)b * 40 + ((ks) >> 3) + g) * 256 + r) * 8,    \
                  (char*)bs_[buf] + s * 16);                                   \
    }                                                                          \
  }

#define LOAD_AF(dst, ks)                                                       \
  {                                                                            \
    _Pragma("unroll")                                                          \
    for (int am = 0; am < 4; ++am) {                                           \
      const int row = m0 + am * 16 + lr;                                       \
      dst[am] = *(const short8*)(gA + ((((ks) >> 3) + lg) * 256 + row) * 8);   \
    }                                                                          \
  }

  short8 afA[4], afB[4];
  STAGE_B2(0, 0);
  LOAD_AF(afA, 0);
  __syncthreads();

  #pragma unroll
  for (int kt = 0; kt < 10; ++kt) {
    const int cur = kt & 1;
    if (kt < 9) {
      STAGE_B2(cur ^ 1, (kt + 1) * 32);
      if (kt & 1) { LOAD_AF(afA, (kt + 1) * 32); }
      else        { LOAD_AF(afB, (kt + 1) * 32); }
    }

    short8 bf[4];
    #pragma unroll
    for (int bn = 0; bn < 4; ++bn) {
      const int row = wn * 64 + bn * 16 + lr;
      bf[bn] = *(const short8*)(bs_[cur] + (lg * 256 + row) * 8);
    }
    #pragma unroll
    for (int am = 0; am < 4; ++am)
      #pragma unroll
      for (int bn = 0; bn < 4; ++bn)
        acc[am][bn] = __builtin_amdgcn_mfma_f32_16x16x32_bf16(
            (kt & 1) ? afB[am] : afA[am], bf[bn], acc[am][bn], 0, 0, 0);

    if (kt < 9) __syncthreads();   // kt==9: nothing staged after -> skip
  }
#undef STAGE_B2
#undef LOAD_AF

  // ---- fused LayerNorm over 256 channels (64 rows/block) ----
  #pragma unroll
  for (int am = 0; am < 4; ++am) {
    #pragma unroll
    for (int rg = 0; rg < 4; ++rg) {
      float s = 0.f, q2 = 0.f;
      #pragma unroll
      for (int bn = 0; bn < 4; ++bn) {
        const float v = acc[am][bn][rg];
        s += v; q2 += v * v;
      }
      #pragma unroll
      for (int off = 1; off < 16; off <<= 1) {
        s  += __shfl_xor(s, off);
        q2 += __shfl_xor(q2, off);
      }
      if (lr == 0) {
        const int row = am * 16 + lg * 4 + rg;
        reds[row][wn] = s; redq[row][wn] = q2;
      }
    }
  }
  __syncthreads();
  if (t < 64) {
    const float S = reds[t][0] + reds[t][1] + reds[t][2] + reds[t][3];
    const float Q = redq[t][0] + redq[t][1] + redq[t][2] + redq[t][3];
    const float mu = S * (1.0f / 256.0f);
    const float var = Q * (1.0f / 256.0f) - mu * mu;
    muv[t] = mu;
    rsv[t] = rsqrtf(var + LN_EPS);
  }
  __syncthreads();

  #pragma unroll
  for (int bn = 0; bn < 4; ++bn) {
    const int col = wn * 64 + bn * 16 + lr;
    const float g = gamma[col], be = beta[col];
    #pragma unroll
    for (int am = 0; am < 4; ++am) {
      #pragma unroll
      for (int rg = 0; rg < 4; ++rg) {
        const int row = am * 16 + lg * 4 + rg;
        out[((size_t)b * 256 + m0 + row) * 256 + col] =
            (acc[am][bn][rg] - muv[row]) * rsv[row] * g + be;
      }
    }
  }
}

extern "C" void kernel_launch(void* const* d_in, const int* in_sizes, int n_in,
                              void* d_out, int out_size, void* d_ws, size_t ws_size,
                              hipStream_t stream) {
  const float* query = (const float*)d_in[0];
  const float* value = (const float*)d_in[1];
  const float* w     = (const float*)d_in[2];
  const float* bl    = (const float*)d_in[3];
  const float* gamma = (const float*)d_in[4];
  const float* beta  = (const float*)d_in[5];
  float* out = (float*)d_out;

  uint16_t* rTk  = (uint16_t*)d_ws;                      // 256*40*256*8 bf16
  uint16_t* pwk  = rTk + (size_t)NB * 40 * 256 * 8;      // 256*40*256*8 bf16
  uint16_t* w3tk = pwk + (size_t)NB * 40 * 256 * 8;      // 32*320*8 bf16
  float*    w012 = (float*)(w3tk + (size_t)32 * NPW * 8);// 3*256 fp32

  hipLaunchKernelGGL(wprep_kernel, dim3(NCOL), dim3(256), 0, stream, w, w3tk, w012);
  hipLaunchKernelGGL(fused1_kernel, dim3(NB * 14), dim3(512), 0, stream,
                     query, value, w012, bl, w3tk, rTk, pwk);
  hipLaunchKernelGGL(gemm2_kernel, dim3(NB * 4), dim3(256), 0, stream,
                     pwk, rTk, gamma, beta, out);
}

// Round 24
// 86.950 us; speedup vs baseline: 1.0108x; 1.0108x over previous
//
#include <hip/hip_runtime.h>
#include <cstddef>
#include <cstdint>

#define NB 256
#define CH 256
#define NTOK 320
#define NPW 320
#define NCOL 323
#define LN_EPS 1e-5f

typedef short short8 __attribute__((ext_vector_type(8)));
typedef float floatx4 __attribute__((ext_vector_type(4)));

__device__ __forceinline__ uint16_t f2bf(float f) {
  uint32_t u = __builtin_bit_cast(uint32_t, f);
  u += 0x7FFFu + ((u >> 16) & 1u);          // round-to-nearest-even
  return (uint16_t)(u >> 16);
}

__device__ __forceinline__ void gload_lds16(const void* g, void* l) {
  __builtin_amdgcn_global_load_lds(
      (const __attribute__((address_space(1))) unsigned int*)g,
      (__attribute__((address_space(3))) unsigned int*)l, 16, 0, 0);
}

// ------ K00: w3tk[k/8][n][k%8] = bf16(w[k][3+n]); w012[tap][k] --------------
__global__ __launch_bounds__(256) void wprep_kernel(
    const float* __restrict__ w, uint16_t* __restrict__ w3tk,
    float* __restrict__ w012) {
  const int n = blockIdx.x;     // 0..322
  const int k = threadIdx.x;    // 0..255
  if (n < NPW) w3tk[(((k >> 3) * NPW) + n) * 8 + (k & 7)] = f2bf(w[k * NCOL + 3 + n]);
  else         w012[(n - NPW) * 256 + k] = w[k * NCOL + (n - NPW)];
}

// ------ K1: FUSED prep (roles 0-9) | gemm1 (roles 10-13) --------------------
// Best-known config (r22): XCD-chunked roles, narrow T5 setprio, A-tile XOR
// swizzle slot = g*128 + (row ^ (g<<1)) on write AND read (bank conflicts 0).
__global__ __launch_bounds__(512) void fused1_kernel(
    const float* __restrict__ query, const float* __restrict__ value,
    const float* __restrict__ w012, const float* __restrict__ bl,
    const uint16_t* __restrict__ w3tk,
    uint16_t* __restrict__ rTk, uint16_t* __restrict__ pwk)
{
  __shared__ __align__(16) char smem[36864];
  const int bid = blockIdx.x;
  const int wg  = ((bid & 7) * (NB * 14 / 8)) + (bid >> 3);  // XCD chunking
  const int b   = wg / 14;
  const int role = wg % 14;
  const int t   = threadIdx.x;      // 0..511
  const int wid = t >> 6, lane = t & 63;

  if (role < 10) {
    // =================== prep role ===================
    uint16_t (*rbuf)[256] = (uint16_t(*)[256])smem;   // 16 KB conv output
    const int tile = role;
    const int n0   = tile * 32;
    const bool isval = (tile < 8);
    const float* src = isval ? (value + ((size_t)b * 256 + n0) * CH)
                             : (query + ((size_t)b * 64 + (n0 - 256)) * CH);
    float4 xv[4];
    #pragma unroll
    for (int q = 0; q < 4; ++q)
      xv[q] = *(const float4*)(src + q * 2048 + t * 4);
    const float4 w0 = *(const float4*)(w012 + lane * 4);
    const float4 w1 = *(const float4*)(w012 + 256 + lane * 4);
    const float4 w2 = *(const float4*)(w012 + 512 + lane * 4);
    const float bl0 = bl[0], bl1 = bl[1], bl2 = bl[2];

    #pragma unroll
    for (int q = 0; q < 4; ++q) {
      float p0 = xv[q].x * w0.x, p1 = xv[q].x * w1.x, p2 = xv[q].x * w2.x;
      p0 = fmaf(xv[q].y, w0.y, p0); p1 = fmaf(xv[q].y, w1.y, p1); p2 = fmaf(xv[q].y, w2.y, p2);
      p0 = fmaf(xv[q].z, w0.z, p0); p1 = fmaf(xv[q].z, w1.z, p1); p2 = fmaf(xv[q].z, w2.z, p2);
      p0 = fmaf(xv[q].w, w0.w, p0); p1 = fmaf(xv[q].w, w1.w, p1); p2 = fmaf(xv[q].w, w2.w, p2);
      #pragma unroll
      for (int off = 32; off; off >>= 1) {
        p0 += __shfl_xor(p0, off);
        p1 += __shfl_xor(p1, off);
        p2 += __shfl_xor(p2, off);
      }
      const float d0 = p0 + bl0, d1 = p1 + bl1, d2 = p2 + bl2;
      float xm = __shfl_up(xv[q].w, 1);   if (lane == 0)  xm = 0.0f;
      float xp = __shfl_down(xv[q].x, 1); if (lane == 63) xp = 0.0f;
      const float o0 = fmaf(d0, xm,       fmaf(d1, xv[q].x, d2 * xv[q].y));
      const float o1 = fmaf(d0, xv[q].x,  fmaf(d1, xv[q].y, d2 * xv[q].z));
      const float o2 = fmaf(d0, xv[q].y,  fmaf(d1, xv[q].z, d2 * xv[q].w));
      const float o3 = fmaf(d0, xv[q].z,  fmaf(d1, xv[q].w, d2 * xp));
      ushort4 h;
      h.x = f2bf(fmaxf(o0, 0.0f)); h.y = f2bf(fmaxf(o1, 0.0f));
      h.z = f2bf(fmaxf(o2, 0.0f)); h.w = f2bf(fmaxf(o3, 0.0f));
      *(ushort4*)&rbuf[q * 8 + wid][lane * 4] = h;
    }
    __syncthreads();

    const int c = t & 255, half = t >> 8;
    uint16_t hbuf[16];
    #pragma unroll
    for (int j = 0; j < 16; ++j) hbuf[j] = rbuf[half * 16 + j][c];
    const int g0 = tile * 4 + half * 2;
    *(uint4*)(rTk + (((size_t)b * 40 + g0)     * 256 + c) * 8) = ((const uint4*)hbuf)[0];
    *(uint4*)(rTk + (((size_t)b * 40 + g0 + 1) * 256 + c) * 8) = ((const uint4*)hbuf)[1];

  } else {
    // =================== gemm1 role (8 waves, 4M x 2N) ==============
    uint16_t* as_ = (uint16_t*)smem;              // [2][4096] = 2 x 8 KB
    uint16_t* bs_ = (uint16_t*)(smem + 16384);    // [2][5120] = 2 x 10 KB
    const int sub = role - 10;                    // 0..3
    const int m0  = (sub >> 1) * 128;
    const int n0  = (sub & 1) * 160;
    const int wm = wid >> 1, wn = wid & 1;
    const int lr = lane & 15, lg = lane >> 4;

    const float* gA = value + ((size_t)b * 256 + m0) * 256;

    floatx4 acc[2][5];
    #pragma unroll
    for (int i = 0; i < 2; ++i)
      #pragma unroll
      for (int j = 0; j < 5; ++j)
        acc[i][j] = (floatx4)0.0f;

#define STAGE_B(buf, ks)                                                       \
  {                                                                            \
    {                                                                          \
      const int s = t;                                                         \
      const int g = s / 160, r = s - g * 160;                                  \
      gload_lds16(w3tk + ((((ks) >> 3) + g) * (size_t)NPW + n0 + r) * 8,       \
                  bs_ + (size_t)(buf)*5120 + s * 8);                           \
    }                                                                          \
    if (t < 128) {                                                             \
      const int s = 512 + t;                                                   \
      const int g = s / 160, r = s - g * 160;                                  \
      gload_lds16(w3tk + ((((ks) >> 3) + g) * (size_t)NPW + n0 + r) * 8,       \
                  bs_ + (size_t)(buf)*5120 + s * 8);                           \
    }                                                                          \
  }

#define LOAD_A(ks)                                                             \
  {                                                                            \
    const int row = t >> 2, g = t & 3;                                         \
    const float* p = gA + (size_t)row * 256 + (ks) + g * 8;                    \
    areg0 = *(const float4*)p;                                                 \
    areg1 = *(const float4*)(p + 4);                                           \
  }

#define WRITE_A(buf)                                                           \
  {                                                                            \
    const int row = t >> 2, g = t & 3;                                         \
    short8 h;                                                                  \
    h[0] = (short)f2bf(areg0.x); h[1] = (short)f2bf(areg0.y);                  \
    h[2] = (short)f2bf(areg0.z); h[3] = (short)f2bf(areg0.w);                  \
    h[4] = (short)f2bf(areg1.x); h[5] = (short)f2bf(areg1.y);                  \
    h[6] = (short)f2bf(areg1.z); h[7] = (short)f2bf(areg1.w);                  \
    *(short8*)((char*)(as_ + (size_t)(buf)*4096) +                             \
               (g * 128 + (row ^ (g << 1))) * 16) = h;                         \
  }

    float4 areg0, areg1;
    LOAD_A(0);
    STAGE_B(0, 0);
    WRITE_A(0);
    __syncthreads();

    for (int kt = 0; kt < 8; ++kt) {
      const int cur = kt & 1;
      if (kt < 7) {
        STAGE_B(cur ^ 1, (kt + 1) * 32);
        LOAD_A((kt + 1) * 32);
      }

      short8 af[2], bf[5];
      #pragma unroll
      for (int am = 0; am < 2; ++am) {
        const int row = wm * 32 + am * 16 + lr;
        af[am] = *(const short8*)(as_ + (size_t)cur * 4096 +
                                  (lg * 128 + (row ^ (lg << 1))) * 8);
      }
      #pragma unroll
      for (int bn = 0; bn < 5; ++bn) {
        const int row = wn * 80 + bn * 16 + lr;
        bf[bn] = *(const short8*)(bs_ + (size_t)cur * 5120 + (lg * 160 + row) * 8);
      }
      __builtin_amdgcn_s_setprio(1);          // T5: favor MFMA waves vs prep
      #pragma unroll
      for (int am = 0; am < 2; ++am)
        #pragma unroll
        for (int bn = 0; bn < 5; ++bn)
          acc[am][bn] = __builtin_amdgcn_mfma_f32_16x16x32_bf16(
              af[am], bf[bn], acc[am][bn], 0, 0, 0);
      __builtin_amdgcn_s_setprio(0);

      if (kt < 7) {
        WRITE_A(cur ^ 1);
        __syncthreads();     // protects bs_/as_[cur] reads vs next stage
      }
      // kt==7: no further staging -> final barrier is dead, skip it
    }
#undef STAGE_B
#undef LOAD_A
#undef WRITE_A

    #pragma unroll
    for (int bn = 0; bn < 5; ++bn) {
      const int col = n0 + wn * 80 + bn * 16 + lr;
      const float bias = bl[3 + col];
      #pragma unroll
      for (int am = 0; am < 2; ++am) {
        #pragma unroll
        for (int rg = 0; rg < 4; ++rg) {
          const int row = m0 + wm * 32 + am * 16 + lg * 4 + rg;
          pwk[(((size_t)b * 40 + (col >> 3)) * 256 + row) * 8 + (col & 7)] =
              f2bf(acc[am][bn][rg] + bias);
        }
      }
    }
  }
}

// ------ K2: out = LN(pwk @ rTk^T) * gamma + beta  (MFMA bf16) ---------------
// Best-known config (r22): 512 threads / 8 waves (2M x 4N), BM=128, BN=256.
// A-frags direct from pwk; B double-buffered in LDS; direct stores.
__global__ __launch_bounds__(512) void gemm2_kernel(
    const uint16_t* __restrict__ pwk, const uint16_t* __restrict__ rTk,
    const float* __restrict__ gamma, const float* __restrict__ beta,
    float* __restrict__ out)
{
  __shared__ uint16_t bs_[2][8192];    // 2 x 16 KB (B: 256x32)
  __shared__ float reds[128][4], redq[128][4];   // 4 KB
  __shared__ float muv[128], rsv[128];           // 1 KB
  const int t   = threadIdx.x;          // 0..511
  const int tid = ((blockIdx.x & 7) << 6) + (blockIdx.x >> 3);  // XCD swizzle
  const int b   = tid >> 1;
  const int m0  = (tid & 1) * 128;
  const int wid = t >> 6, lane = t & 63;
  const int wm = wid >> 2, wn = wid & 3;
  const int lr = lane & 15, lg = lane >> 4;

  const uint16_t* gA = pwk + (size_t)b * 40 * 256 * 8;

  floatx4 acc[4][4];
  #pragma unroll
  for (int i = 0; i < 4; ++i)
    #pragma unroll
    for (int j = 0; j < 4; ++j)
      acc[i][j] = (floatx4)0.0f;

#define STAGE_B2(buf, ks)                                                      \
  {                                                                            \
    _Pragma("unroll")                                                          \
    for (int q = 0; q < 2; ++q) {                                              \
      const int s = q * 512 + t;                                               \
      const int g = s >> 8, r = s & 255;                                       \
      gload_lds16(rTk + (((size_t)b * 40 + ((ks) >> 3) + g) * 256 + r) * 8,    \
                  (char*)bs_[buf] + s * 16);                                   \
    }                                                                          \
  }

#define LOAD_AF(dst, ks)                                                       \
  {                                                                            \
    _Pragma("unroll")                                                          \
    for (int am = 0; am < 4; ++am) {                                           \
      const int row = m0 + wm * 64 + am * 16 + lr;                             \
      dst[am] = *(const short8*)(gA + ((((ks) >> 3) + lg) * 256 + row) * 8);   \
    }                                                                          \
  }

  short8 afA[4], afB[4];
  STAGE_B2(0, 0);
  LOAD_AF(afA, 0);
  __syncthreads();

  #pragma unroll
  for (int kt = 0; kt < 10; ++kt) {
    const int cur = kt & 1;
    if (kt < 9) {
      STAGE_B2(cur ^ 1, (kt + 1) * 32);
      if (kt & 1) { LOAD_AF(afA, (kt + 1) * 32); }
      else        { LOAD_AF(afB, (kt + 1) * 32); }
    }

    short8 bf[4];
    #pragma unroll
    for (int bn = 0; bn < 4; ++bn) {
      const int row = wn * 64 + bn * 16 + lr;
      bf[bn] = *(const short8*)(bs_[cur] + (lg * 256 + row) * 8);
    }
    #pragma unroll
    for (int am = 0; am < 4; ++am)
      #pragma unroll
      for (int bn = 0; bn < 4; ++bn)
        acc[am][bn] = __builtin_amdgcn_mfma_f32_16x16x32_bf16(
            (kt & 1) ? afB[am] : afA[am], bf[bn], acc[am][bn], 0, 0, 0);

    if (kt < 9) __syncthreads();   // kt==9: nothing staged after -> skip
  }
#undef STAGE_B2
#undef LOAD_AF

  // ---- fused LayerNorm over 256 channels (128 rows/block) ----
  #pragma unroll
  for (int am = 0; am < 4; ++am) {
    #pragma unroll
    for (int rg = 0; rg < 4; ++rg) {
      float s = 0.f, q2 = 0.f;
      #pragma unroll
      for (int bn = 0; bn < 4; ++bn) {
        const float v = acc[am][bn][rg];
        s += v; q2 += v * v;
      }
      #pragma unroll
      for (int off = 1; off < 16; off <<= 1) {
        s  += __shfl_xor(s, off);
        q2 += __shfl_xor(q2, off);
      }
      if (lr == 0) {
        const int row = wm * 64 + am * 16 + lg * 4 + rg;
        reds[row][wn] = s; redq[row][wn] = q2;
      }
    }
  }
  __syncthreads();
  if (t < 128) {
    const float S = reds[t][0] + reds[t][1] + reds[t][2] + reds[t][3];
    const float Q = redq[t][0] + redq[t][1] + redq[t][2] + redq[t][3];
    const float mu = S * (1.0f / 256.0f);
    const float var = Q * (1.0f / 256.0f) - mu * mu;
    muv[t] = mu;
    rsv[t] = rsqrtf(var + LN_EPS);
  }
  __syncthreads();

  #pragma unroll
  for (int bn = 0; bn < 4; ++bn) {
    const int col = wn * 64 + bn * 16 + lr;
    const float g = gamma[col], be = beta[col];
    #pragma unroll
    for (int am = 0; am < 4; ++am) {
      #pragma unroll
      for (int rg = 0; rg < 4; ++rg) {
        const int row = wm * 64 + am * 16 + lg * 4 + rg;
        out[((size_t)b * 256 + m0 + row) * 256 + col] =
            (acc[am][bn][rg] - muv[row]) * rsv[row] * g + be;
      }
    }
  }
}

extern "C" void kernel_launch(void* const* d_in, const int* in_sizes, int n_in,
                              void* d_out, int out_size, void* d_ws, size_t ws_size,
                              hipStream_t stream) {
  const float* query = (const float*)d_in[0];
  const float* value = (const float*)d_in[1];
  const float* w     = (const float*)d_in[2];
  const float* bl    = (const float*)d_in[3];
  const float* gamma = (const float*)d_in[4];
  const float* beta  = (const float*)d_in[5];
  float* out = (float*)d_out;

  uint16_t* rTk  = (uint16_t*)d_ws;                      // 256*40*256*8 bf16
  uint16_t* pwk  = rTk + (size_t)NB * 40 * 256 * 8;      // 256*40*256*8 bf16
  uint16_t* w3tk = pwk + (size_t)NB * 40 * 256 * 8;      // 32*320*8 bf16
  float*    w012 = (float*)(w3tk + (size_t)32 * NPW * 8);// 3*256 fp32

  hipLaunchKernelGGL(wprep_kernel, dim3(NCOL), dim3(256), 0, stream, w, w3tk, w012);
  hipLaunchKernelGGL(fused1_kernel, dim3(NB * 14), dim3(512), 0, stream,
                     query, value, w012, bl, w3tk, rTk, pwk);
  hipLaunchKernelGGL(gemm2_kernel, dim3(NB * 2), dim3(512), 0, stream,
                     pwk, rTk, gamma, beta, out);
}